// Round 2
// baseline (374.577 us; speedup 1.0000x reference)
//
#include <hip/hip_runtime.h>
#include <hip/hip_cooperative_groups.h>
#include <cstdint>
#include <cstddef>

namespace cg = cooperative_groups;

#define BB 4
#define CC 19
#define HH 512
#define WW 1024
#define HW (HH*WW)          // 524288
#define HW4 (HW/4)          // 131072
#define BHW (BB*HW)
#define KTOP 256
#define EPSF 1e-6f
#define NB1 4096            // coarse bins: key >> 20
#define NB2 8192            // refine bins: (key >> 7) & 0x1FFF
#define LSTRIDE 1032        // padded LDS row stride, data at col 4..1027
#define LOGC 2.9444389791664403f   // ln(19)

// fused geometry: 4 images x 64 segments x 8 rows = 256 blocks (1/CU resident)
#define NSEG 64
#define RPB 8
// fallback geometry (proven 4-kernel pipeline)
#define SEGF 128

__device__ __forceinline__ unsigned int sortable(float x) {
    unsigned int u = __float_as_uint(x);
    return (u & 0x80000000u) ? ~u : (u | 0x80000000u);
}
__device__ __forceinline__ float unsortable(unsigned int K) {
    unsigned int u = (K & 0x80000000u) ? (K & 0x7FFFFFFFu) : ~K;
    return __uint_as_float(u);
}
// agent-scope atomics: force cross-XCD-visible traffic (Guideline 16)
__device__ __forceinline__ unsigned int agld(const unsigned int* p) {
    return __hip_atomic_load(p, __ATOMIC_RELAXED, __HIP_MEMORY_SCOPE_AGENT);
}
__device__ __forceinline__ void agst(unsigned int* p, unsigned int v) {
    __hip_atomic_store(p, v, __ATOMIC_RELAXED, __HIP_MEMORY_SCOPE_AGENT);
}

// ======================= fused cooperative kernel =======================
struct P1Mem8 {
    float ent_s[(RPB + 2) * LSTRIDE];          // 41280 B
    unsigned char pred_s[(RPB + 2) * LSTRIDE]; // 10320 B
    unsigned int lh1[NB1];                     // 16384 B
};
struct P2Mem8 {
    unsigned int lh2[NB2];                     // 32768 B
    float ls2[NB2];                            // 32768 B
};
union UMem8 { P1Mem8 p1; P2Mem8 p2; };         // 67984 B

__device__ __forceinline__ void sel_coarse(const unsigned int* __restrict__ hb,
                                           int rem, unsigned int* cs, unsigned int* bs,
                                           int* s3, int* bin_out, int* rem_out) {
    int t = threadIdx.x;
    unsigned int s = 0;
#pragma unroll
    for (int i = 0; i < 16; ++i) s += agld(&hb[t * 16 + i]);
    cs[t] = s;
    __syncthreads();
    for (int d = 1; d < 256; d <<= 1) {            // suffix scan
        unsigned int v = (t + d < 256) ? cs[t + d] : 0;
        __syncthreads();
        cs[t] += v;
        __syncthreads();
    }
    unsigned int St = cs[t];
    unsigned int St1 = (t < 255) ? cs[t + 1] : 0;
    if ((int)St >= rem && (t == 255 || (int)St1 < rem)) {
        s3[0] = t; s3[2] = rem - (int)St1;
    }
    __syncthreads();
    int chunk = s3[0], rem2 = s3[2];
    if (t < 16) bs[t] = agld(&hb[chunk * 16 + t]);
    __syncthreads();
    for (int d = 1; d < 16; d <<= 1) {
        unsigned int v = (t < 16 && t + d < 16) ? bs[t + d] : 0;
        __syncthreads();
        if (t < 16) bs[t] += v;
        __syncthreads();
    }
    if (t < 16) {
        unsigned int Sb = bs[t];
        unsigned int Sb1 = (t < 15) ? bs[t + 1] : 0;
        if ((int)Sb >= rem2 && (t == 15 || (int)Sb1 < rem2)) {
            s3[1] = chunk * 16 + t; s3[2] = rem2 - (int)Sb1;
        }
    }
    __syncthreads();
    *bin_out = s3[1];
    *rem_out = s3[2];
}

__device__ __forceinline__ void sel_fine(const unsigned int* __restrict__ hb,
                                         int rem, unsigned int* cs, unsigned int* bs,
                                         int* s3, int* bin_out, int* rem_out) {
    int t = threadIdx.x;
    unsigned int s = 0;
#pragma unroll 8
    for (int i = 0; i < 32; ++i) s += agld(&hb[t * 32 + i]);
    cs[t] = s;
    __syncthreads();
    for (int d = 1; d < 256; d <<= 1) {
        unsigned int v = (t + d < 256) ? cs[t + d] : 0;
        __syncthreads();
        cs[t] += v;
        __syncthreads();
    }
    unsigned int St = cs[t];
    unsigned int St1 = (t < 255) ? cs[t + 1] : 0;
    if ((int)St >= rem && (t == 255 || (int)St1 < rem)) {
        s3[0] = t; s3[2] = rem - (int)St1;
    }
    __syncthreads();
    int chunk = s3[0], rem2 = s3[2];
    if (t < 32) bs[t] = agld(&hb[chunk * 32 + t]);
    __syncthreads();
    for (int d = 1; d < 32; d <<= 1) {
        unsigned int v = (t < 32 && t + d < 32) ? bs[t + d] : 0;
        __syncthreads();
        if (t < 32) bs[t] += v;
        __syncthreads();
    }
    if (t < 32) {
        unsigned int Sb = bs[t];
        unsigned int Sb1 = (t < 31) ? bs[t + 1] : 0;
        if ((int)Sb >= rem2 && (t == 31 || (int)Sb1 < rem2)) {
            s3[1] = chunk * 32 + t; s3[2] = rem2 - (int)Sb1;
        }
    }
    __syncthreads();
    *bin_out = s3[1];
    *rem_out = s3[2];
}

__global__ __launch_bounds__(256, 2) void k_fused8(const float* __restrict__ logit,
                                                   float* __restrict__ ent,
                                                   unsigned char* __restrict__ pred,
                                                   unsigned int* __restrict__ histb,
                                                   float* __restrict__ out) {
    __shared__ __align__(16) UMem8 U;
    __shared__ float lgt[48];
    __shared__ unsigned int cs[256];
    __shared__ unsigned int bs[32];
    __shared__ int s3[3];
    __shared__ float red[4];
    __shared__ float rs[256];

    cg::grid_group grid = cg::this_grid();
    int tid = threadIdx.x;
    int b = blockIdx.x >> 6;            // image
    int seg = blockIdx.x & (NSEG - 1);  // 8-row segment
    int r0 = seg * RPB;

    unsigned int* hist1 = histb;                      // 4*4096 words
    unsigned int* hist2 = histb + 16384;              // 4*8192 words
    float*        hsum  = (float*)(histb + 49152);    // 4*8192 words

    // ---------------- P0: zero-init + entropy/argmax (own 8 rows) ----------------
    int gid = blockIdx.x * 256 + tid;                 // 0..65535
    for (int i = gid; i < 81920; i += 256 * 256) agst(&histb[i], 0u);
    if (gid < BB) agst((unsigned int*)&out[gid], 0u);
    if (tid < 48) {
        int nvi = tid >> 4, cnt = tid & 15;
        float nv = (nvi == 0) ? 4.f : (nvi == 1) ? 6.f : 9.f;
        lgt[tid] = __logf((float)cnt / nv + EPSF);
    }
    for (int i = tid; i < (RPB + 2) * LSTRIDE; i += 256) { U.p1.ent_s[i] = 0.f; U.p1.pred_s[i] = 255; }
    for (int i = tid; i < NB1; i += 256) U.p1.lh1[i] = 0;
    __syncthreads();

    {
        const float4* bb4 = (const float4*)logit + (size_t)b * CC * HW4;
        int q0 = r0 * 256;
#pragma unroll
        for (int it = 0; it < RPB; ++it) {
            int q = q0 + it * 256 + tid;
            const float4* basep = bb4 + q;
            float e0 = 0.f, e1 = 0.f, e2 = 0.f, e3 = 0.f;
            float m0 = -1.f, m1 = -1.f, m2 = -1.f, m3 = -1.f;
            int a0 = 0, a1 = 0, a2 = 0, a3 = 0;
#pragma unroll
            for (int c = 0; c < CC; ++c) {
                float4 p = basep[(size_t)c * HW4];
                e0 -= p.x * __logf(p.x + EPSF); if (p.x > m0) { m0 = p.x; a0 = c; }
                e1 -= p.y * __logf(p.y + EPSF); if (p.y > m1) { m1 = p.y; a1 = c; }
                e2 -= p.z * __logf(p.z + EPSF); if (p.z > m2) { m2 = p.z; a2 = c; }
                e3 -= p.w * __logf(p.w + EPSF); if (p.w > m3) { m3 = p.w; a3 = c; }
            }
            // LDS row (it+1) == global row r0+it; interior rows never hit global
            *(float4*)&U.p1.ent_s[(it + 1) * LSTRIDE + 4 + tid * 4] = make_float4(e0, e1, e2, e3);
            U.p1.pred_s[(it + 1) * LSTRIDE + 4 + tid * 4 + 0] = (unsigned char)a0;
            U.p1.pred_s[(it + 1) * LSTRIDE + 4 + tid * 4 + 1] = (unsigned char)a1;
            U.p1.pred_s[(it + 1) * LSTRIDE + 4 + tid * 4 + 2] = (unsigned char)a2;
            U.p1.pred_s[(it + 1) * LSTRIDE + 4 + tid * 4 + 3] = (unsigned char)a3;
            if (it == 0 || it == RPB - 1) {           // boundary rows -> global, agent scope
                unsigned int* ep = (unsigned int*)ent + ((size_t)b * HW4 + q) * 4;
                agst(ep + 0, __float_as_uint(e0));
                agst(ep + 1, __float_as_uint(e1));
                agst(ep + 2, __float_as_uint(e2));
                agst(ep + 3, __float_as_uint(e3));
                unsigned int pw = (unsigned int)a0 | ((unsigned int)a1 << 8) |
                                  ((unsigned int)a2 << 16) | ((unsigned int)a3 << 24);
                agst((unsigned int*)pred + (size_t)b * HW4 + q, pw);
            }
        }
    }
    grid.sync();

    // ---------------- P1: stage 2 halo rows, score 32 pixels/thread ----------------
    for (int i = tid; i < 512; i += 256) {            // 2 rows x 256 quads
        int top = i >> 8;                             // 0 or 1
        int rr = top * (RPB + 1);                     // LDS row 0 or 9
        int c4 = i & 255;
        int g = r0 - 1 + top * (RPB + 1);             // global row r0-1 or r0+8
        if (g >= 0 && g < HH) {
            const unsigned int* es4 = (const unsigned int*)ent + ((size_t)b * HW4 + (size_t)g * 256 + c4) * 4;
            float4 v;
            v.x = __uint_as_float(agld(es4 + 0));
            v.y = __uint_as_float(agld(es4 + 1));
            v.z = __uint_as_float(agld(es4 + 2));
            v.w = __uint_as_float(agld(es4 + 3));
            *(float4*)&U.p1.ent_s[rr * LSTRIDE + 4 + c4 * 4] = v;
            unsigned int pw = agld((const unsigned int*)pred + (size_t)b * HW4 + (size_t)g * 256 + c4);
            *(unsigned int*)&U.p1.pred_s[rr * LSTRIDE + 4 + c4 * 4] = pw;
        }
    }
    __syncthreads();

    // thread t owns pixels (rows r0..r0+7, cols 4t..4t+3); scores stay in regs
    float sv[4 * RPB];
#pragma unroll
    for (int k = 0; k < RPB; ++k) {
        float r3[3][6];
        int p3[3][6];
#pragma unroll
        for (int rr = 0; rr < 3; ++rr) {
            const float* rowp = &U.p1.ent_s[(k + rr) * LSTRIDE + 4];
            const unsigned char* prow = &U.p1.pred_s[(k + rr) * LSTRIDE + 4];
            float4 m = *(const float4*)&rowp[tid * 4];
            r3[rr][0] = rowp[tid * 4 - 1];            // col pad (0) at w==0 edge
            r3[rr][1] = m.x; r3[rr][2] = m.y; r3[rr][3] = m.z; r3[rr][4] = m.w;
            r3[rr][5] = rowp[tid * 4 + 4];
            uchar4 pm = *(const uchar4*)&prow[tid * 4];
            p3[rr][0] = prow[tid * 4 - 1];            // 255 pad
            p3[rr][1] = pm.x; p3[rr][2] = pm.y; p3[rr][3] = pm.z; p3[rr][4] = pm.w;
            p3[rr][5] = prow[tid * 4 + 4];
        }
        int h = r0 + k;
        int hn = (h > 0) + (h < HH - 1) + 1;
#pragma unroll
        for (int q = 0; q < 4; ++q) {
            int w = tid * 4 + q;
            float es = 0.f;
#pragma unroll
            for (int i = 0; i < 9; ++i) es += r3[i / 3][q + i % 3];   // same add order
            int cls[9];
#pragma unroll
            for (int i = 0; i < 9; ++i) cls[i] = p3[i / 3][q + i % 3];
            int nv = hn * ((w > 0) + (w < WW - 1) + 1);
            float inv = 1.f / (float)nv;
            int nvi = (nv == 9) ? 2 : ((nv == 6) ? 1 : 0);
            const float* lg = &lgt[nvi * 16];
            float lsum = 0.f;
#pragma unroll
            for (int i = 0; i < 9; ++i) {
                int cnt = 0;
#pragma unroll
                for (int j = 0; j < 9; ++j) cnt += (cls[j] == cls[i]) ? 1 : 0;
                float lv = lg[cnt];
                lsum += (cls[i] != 255) ? lv : 0.f;
            }
            float imp = -inv * lsum;
            float v = (es * (1.f / (9.f * LOGC))) * (imp * (1.f / LOGC));
            sv[k * 4 + q] = v;
            atomicAdd(&U.p1.lh1[sortable(v) >> 20], 1u);
        }
    }
    __syncthreads();
    {
        unsigned int* hb = hist1 + (size_t)b * NB1;
        for (int i = tid; i < NB1; i += 256) {
            unsigned int c = U.p1.lh1[i];
            if (c) atomicAdd(&hb[i], c);
        }
    }
    grid.sync();

    // ---------------- P2: coarse select + refine hist + strict-above sum ----------------
    int bin1, rem1;
    sel_coarse(hist1 + (size_t)b * NB1, KTOP, cs, bs, s3, &bin1, &rem1);
    unsigned int t1 = (unsigned int)bin1;
    for (int i = tid; i < NB2; i += 256) { U.p2.lh2[i] = 0; U.p2.ls2[i] = 0.f; }
    __syncthreads();
    float sa = 0.f;
#pragma unroll
    for (int j = 0; j < 4 * RPB; ++j) {
        float vv = sv[j];
        unsigned int k = sortable(vv);
        unsigned int cb = k >> 20;
        if (cb > t1) sa += vv;
        else if (cb == t1) {
            int sub = (k >> 7) & 0x1FFF;
            atomicAdd(&U.p2.lh2[sub], 1u);
            atomicAdd(&U.p2.ls2[sub], vv);
        }
    }
    __syncthreads();
    {
        unsigned int* hb = hist2 + (size_t)b * NB2;
        float* sb = hsum + (size_t)b * NB2;
        for (int i = tid; i < NB2; i += 256) {
            unsigned int c = U.p2.lh2[i];
            if (c) { atomicAdd(&hb[i], c); atomicAdd(&sb[i], U.p2.ls2[i]); }
        }
    }
#pragma unroll
    for (int d = 32; d; d >>= 1) sa += __shfl_down(sa, d);
    if ((tid & 63) == 0) red[tid >> 6] = sa;
    __syncthreads();
    if (tid == 0) {
        float tt = red[0] + red[1] + red[2] + red[3];
        if (tt != 0.f) atomicAdd(&out[b], tt);
    }
    grid.sync();

    // ---------------- P3: final threshold + tail sums (seg==0 blocks) ----------------
    if (seg == 0) {
        int bin, rem;
        sel_fine(hist2 + (size_t)b * NB2, rem1, cs, bs, s3, &bin, &rem);
        const float* sb = hsum + (size_t)b * NB2;
        float s = 0.f;
        for (int i = tid; i < NB2; i += 256)
            if (i > bin) s += __uint_as_float(agld((const unsigned int*)&sb[i]));
        rs[tid] = s;
        __syncthreads();
        for (int d = 128; d; d >>= 1) {
            if (tid < d) rs[tid] += rs[tid + d];
            __syncthreads();
        }
        if (tid == 0) {
            unsigned int K = (t1 << 20) | ((unsigned int)bin << 7);
            float cur = __uint_as_float(agld((const unsigned int*)&out[b]));
            agst((unsigned int*)&out[b], __float_as_uint(cur + rs[0] + unsortable(K) * (float)rem));
        }
    }
}

// ======================= fallback: proven 4-kernel pipeline =======================
__global__ __launch_bounds__(256) void k_ent(const float4* __restrict__ logit,
                                             float4* __restrict__ ent,
                                             uchar4* __restrict__ pred,
                                             unsigned int* __restrict__ histz,
                                             float* __restrict__ outz) {
    int idx = blockIdx.x * 256 + threadIdx.x;
    if (idx < 81928) histz[idx] = 0;
    if (idx < BB) outz[idx] = 0.f;
    int b = idx >> 17;
    int q = idx & (HW4 - 1);
    const float4* base = logit + (size_t)b * CC * HW4 + q;
    float e0 = 0.f, e1 = 0.f, e2 = 0.f, e3 = 0.f;
    float m0 = -1.f, m1 = -1.f, m2 = -1.f, m3 = -1.f;
    int a0 = 0, a1 = 0, a2 = 0, a3 = 0;
#pragma unroll
    for (int c = 0; c < CC; ++c) {
        float4 p = base[(size_t)c * HW4];
        e0 -= p.x * __logf(p.x + EPSF); if (p.x > m0) { m0 = p.x; a0 = c; }
        e1 -= p.y * __logf(p.y + EPSF); if (p.y > m1) { m1 = p.y; a1 = c; }
        e2 -= p.z * __logf(p.z + EPSF); if (p.z > m2) { m2 = p.z; a2 = c; }
        e3 -= p.w * __logf(p.w + EPSF); if (p.w > m3) { m3 = p.w; a3 = c; }
    }
    ent[idx] = make_float4(e0, e1, e2, e3);
    pred[idx] = make_uchar4((unsigned char)a0, (unsigned char)a1,
                            (unsigned char)a2, (unsigned char)a3);
}

__global__ __launch_bounds__(256) void k_score_hist(const float* __restrict__ ent,
                                                    const unsigned char* __restrict__ pred,
                                                    float* __restrict__ score,
                                                    unsigned int* __restrict__ hist1) {
    __shared__ __align__(16) float ent_s[6 * LSTRIDE];
    __shared__ __align__(16) unsigned char pred_s[6 * LSTRIDE];
    __shared__ unsigned int lh[NB1];
    __shared__ float lgt[48];
    int tid = threadIdx.x;
    int b = blockIdx.x >> 7;
    int seg = blockIdx.x & (SEGF - 1);
    int r0 = seg * 4;

    for (int i = tid; i < 6 * LSTRIDE; i += 256) { ent_s[i] = 0.f; pred_s[i] = 255; }
    for (int i = tid; i < NB1; i += 256) lh[i] = 0;
    if (tid < 48) {
        int nvi = tid >> 4, cnt = tid & 15;
        float nv = (nvi == 0) ? 4.f : (nvi == 1) ? 6.f : 9.f;
        lgt[tid] = __logf((float)cnt / nv + EPSF);
    }
    __syncthreads();

    const float* eb = ent + (size_t)b * HW;
    const unsigned char* pb = pred + (size_t)b * HW;
    for (int i = tid; i < 1536; i += 256) {
        int rr = i >> 8, c4 = i & 255;
        int g = r0 - 1 + rr;
        if (g >= 0 && g < HH) {
            float4 v = *(const float4*)(eb + g * WW + c4 * 4);
            *(float4*)&ent_s[rr * LSTRIDE + 4 + c4 * 4] = v;
            uchar4 pv = *(const uchar4*)(pb + g * WW + c4 * 4);
            *(uchar4*)&pred_s[rr * LSTRIDE + 4 + c4 * 4] = pv;
        }
    }
    __syncthreads();

    float* sbuf = score + (size_t)b * HW;
#pragma unroll
    for (int it = 0; it < 16; ++it) {
        int p = it * 256 + tid;
        int py = p >> 10, px = p & 1023;
        int h = r0 + py, w = px;
        int l0 = py * LSTRIDE + 3 + px;
        float es = 0.f;
        int cls[9];
#pragma unroll
        for (int i = 0; i < 9; ++i) {
            int o = l0 + (i / 3) * LSTRIDE + (i % 3);
            es += ent_s[o];
            cls[i] = pred_s[o];
        }
        int nv = ((h > 0) + (h < HH - 1) + 1) * ((w > 0) + (w < WW - 1) + 1);
        float inv = 1.f / (float)nv;
        int nvi = (nv == 9) ? 2 : ((nv == 6) ? 1 : 0);
        const float* lg = &lgt[nvi * 16];
        float lsum = 0.f;
#pragma unroll
        for (int i = 0; i < 9; ++i) {
            int cnt = 0;
#pragma unroll
            for (int j = 0; j < 9; ++j) cnt += (cls[j] == cls[i]) ? 1 : 0;
            float lv = lg[cnt];
            lsum += (cls[i] != 255) ? lv : 0.f;
        }
        float imp = -inv * lsum;
        float v = (es * (1.f / (9.f * LOGC))) * (imp * (1.f / LOGC));
        sbuf[h * WW + w] = v;
        atomicAdd(&lh[sortable(v) >> 20], 1u);
    }
    __syncthreads();
    unsigned int* hb = hist1 + (size_t)b * NB1;
    for (int i = tid; i < NB1; i += 256) {
        unsigned int c = lh[i];
        if (c) atomicAdd(&hb[i], c);
    }
}

__device__ __forceinline__ void select4k(const unsigned int* __restrict__ hb,
                                         int rem, int* bin_out, int* rem_out) {
    __shared__ unsigned int cs[256];
    __shared__ unsigned int bs[16];
    __shared__ int s_chunk, s_bin, s_rem;
    int t = threadIdx.x;
    unsigned int s = 0;
#pragma unroll
    for (int i = 0; i < 16; ++i) s += hb[t * 16 + i];
    cs[t] = s;
    __syncthreads();
    for (int d = 1; d < 256; d <<= 1) {
        unsigned int v = (t + d < 256) ? cs[t + d] : 0;
        __syncthreads();
        cs[t] += v;
        __syncthreads();
    }
    unsigned int St = cs[t];
    unsigned int St1 = (t < 255) ? cs[t + 1] : 0;
    if ((int)St >= rem && (t == 255 || (int)St1 < rem)) {
        s_chunk = t; s_rem = rem - (int)St1;
    }
    __syncthreads();
    int chunk = s_chunk, rem2 = s_rem;
    if (t < 16) bs[t] = hb[chunk * 16 + t];
    __syncthreads();
    for (int d = 1; d < 16; d <<= 1) {
        unsigned int v = (t < 16 && t + d < 16) ? bs[t + d] : 0;
        __syncthreads();
        if (t < 16) bs[t] += v;
        __syncthreads();
    }
    if (t < 16) {
        unsigned int Sb = bs[t];
        unsigned int Sb1 = (t < 15) ? bs[t + 1] : 0;
        if ((int)Sb >= rem2 && (t == 15 || (int)Sb1 < rem2)) {
            s_bin = chunk * 16 + t; s_rem = rem2 - (int)Sb1;
        }
    }
    __syncthreads();
    *bin_out = s_bin;
    *rem_out = s_rem;
}

__device__ __forceinline__ void select8k(const unsigned int* __restrict__ hb,
                                         int rem, int* bin_out, int* rem_out) {
    __shared__ unsigned int cs[256];
    __shared__ unsigned int bs[32];
    __shared__ int s_chunk, s_bin, s_rem;
    int t = threadIdx.x;
    unsigned int s = 0;
#pragma unroll 8
    for (int i = 0; i < 32; ++i) s += hb[t * 32 + i];
    cs[t] = s;
    __syncthreads();
    for (int d = 1; d < 256; d <<= 1) {
        unsigned int v = (t + d < 256) ? cs[t + d] : 0;
        __syncthreads();
        cs[t] += v;
        __syncthreads();
    }
    unsigned int St = cs[t];
    unsigned int St1 = (t < 255) ? cs[t + 1] : 0;
    if ((int)St >= rem && (t == 255 || (int)St1 < rem)) {
        s_chunk = t; s_rem = rem - (int)St1;
    }
    __syncthreads();
    int chunk = s_chunk, rem2 = s_rem;
    if (t < 32) bs[t] = hb[chunk * 32 + t];
    __syncthreads();
    for (int d = 1; d < 32; d <<= 1) {
        unsigned int v = (t < 32 && t + d < 32) ? bs[t + d] : 0;
        __syncthreads();
        if (t < 32) bs[t] += v;
        __syncthreads();
    }
    if (t < 32) {
        unsigned int Sb = bs[t];
        unsigned int Sb1 = (t < 31) ? bs[t + 1] : 0;
        if ((int)Sb >= rem2 && (t == 31 || (int)Sb1 < rem2)) {
            s_bin = chunk * 32 + t; s_rem = rem2 - (int)Sb1;
        }
    }
    __syncthreads();
    *bin_out = s_bin;
    *rem_out = s_rem;
}

__global__ __launch_bounds__(256) void k_hist2(const float4* __restrict__ score,
                                               const unsigned int* __restrict__ hist1,
                                               unsigned int* __restrict__ hist2,
                                               float* __restrict__ hsum,
                                               unsigned int* __restrict__ T1g,
                                               int* __restrict__ r1g,
                                               float* __restrict__ out) {
    __shared__ unsigned int lh[NB2];
    __shared__ float ls[NB2];
    __shared__ float red[4];
    int b = blockIdx.x >> 7;
    int seg = blockIdx.x & (SEGF - 1);
    int bin1, rem1;
    select4k(hist1 + (size_t)b * NB1, KTOP, &bin1, &rem1);
    unsigned int t1 = (unsigned int)bin1;
    if (seg == 0 && threadIdx.x == 0) { T1g[b] = t1; r1g[b] = rem1; }
    for (int i = threadIdx.x; i < NB2; i += 256) { lh[i] = 0; ls[i] = 0.f; }
    __syncthreads();
    const float4* p = score + ((size_t)b * HW + (size_t)seg * (HW / SEGF)) / 4;
    float sa = 0.f;
    for (int i = threadIdx.x; i < (HW / SEGF) / 4; i += 256) {
        float4 v = p[i];
        float vv[4] = {v.x, v.y, v.z, v.w};
#pragma unroll
        for (int q = 0; q < 4; ++q) {
            unsigned int k = sortable(vv[q]);
            unsigned int cb = k >> 20;
            if (cb > t1) sa += vv[q];
            else if (cb == t1) {
                int sub = (k >> 7) & 0x1FFF;
                atomicAdd(&lh[sub], 1u);
                atomicAdd(&ls[sub], vv[q]);
            }
        }
    }
    __syncthreads();
    unsigned int* hb = hist2 + (size_t)b * NB2;
    float* sb = hsum + (size_t)b * NB2;
    for (int i = threadIdx.x; i < NB2; i += 256) {
        unsigned int c = lh[i];
        if (c) { atomicAdd(&hb[i], c); atomicAdd(&sb[i], ls[i]); }
    }
#pragma unroll
    for (int d = 32; d; d >>= 1) sa += __shfl_down(sa, d);
    if ((threadIdx.x & 63) == 0) red[threadIdx.x >> 6] = sa;
    __syncthreads();
    if (threadIdx.x == 0) {
        float tt = red[0] + red[1] + red[2] + red[3];
        if (tt != 0.f) atomicAdd(&out[b], tt);
    }
}

__global__ __launch_bounds__(256) void k_scan2(const unsigned int* __restrict__ hist2,
                                               const float* __restrict__ hsum,
                                               const unsigned int* __restrict__ T1g,
                                               const int* __restrict__ r1g,
                                               float* __restrict__ out) {
    int b = blockIdx.x;
    int bin, rem;
    select8k(hist2 + (size_t)b * NB2, r1g[b], &bin, &rem);
    __shared__ float rs[256];
    int t = threadIdx.x;
    const float* sb = hsum + (size_t)b * NB2;
    float s = 0.f;
    for (int i = t; i < NB2; i += 256) if (i > bin) s += sb[i];
    rs[t] = s;
    __syncthreads();
    for (int d = 128; d; d >>= 1) {
        if (t < d) rs[t] += rs[t + d];
        __syncthreads();
    }
    if (t == 0) {
        unsigned int K = (T1g[b] << 20) | ((unsigned int)bin << 7);
        out[b] += rs[0] + unsortable(K) * (float)rem;
    }
}

extern "C" void kernel_launch(void* const* d_in, const int* in_sizes, int n_in,
                              void* d_out, int out_size, void* d_ws, size_t ws_size,
                              hipStream_t stream) {
    const float* logit = (const float*)d_in[0];
    float* out = (float*)d_out;
    char* ws = (char*)d_ws;

    // shared workspace layout (both paths)
    float*         ent   = (float*)(ws);                       // 8,388,608 B
    unsigned char* pred  = (unsigned char*)(ws + 8388608);     // 2,097,152 B
    float*         score = (float*)(ws + 10485760);            // 8,388,608 B (fallback only)
    unsigned int*  histb = (unsigned int*)(ws + 18874368);
    unsigned int*  hist1 = histb;
    unsigned int*  hist2 = histb + 16384;
    float*         hsum  = (float*)(histb + 49152);
    unsigned int*  T1g   = histb + 81920;
    int*           r1g   = (int*)(histb + 81924);

    void* args[] = { (void*)&logit, (void*)&ent, (void*)&pred, (void*)&histb, (void*)&out };
    hipError_t err = hipLaunchCooperativeKernel(k_fused8, dim3(BB * NSEG), dim3(256),
                                                args, 0u, stream);
    if (err != hipSuccess) {
        (void)hipGetLastError();   // clear sticky error; fall back to proven pipeline
        k_ent<<<BHW / 4 / 256, 256, 0, stream>>>((const float4*)logit, (float4*)ent,
                                                 (uchar4*)pred, histb, out);
        k_score_hist<<<BB * SEGF, 256, 0, stream>>>(ent, pred, score, hist1);
        k_hist2<<<BB * SEGF, 256, 0, stream>>>((const float4*)score, hist1,
                                               hist2, hsum, T1g, r1g, out);
        k_scan2<<<BB, 256, 0, stream>>>(hist2, hsum, T1g, r1g, out);
    }
}